// Round 1
// baseline (259.053 us; speedup 1.0000x reference)
//
#include <hip/hip_runtime.h>

// ARModel: out[b,t,n,0] = (t==0) ? 0 : x[b,t-1,n,0]*w[0,0,0] + bias[0]
// B=64, T=288, N=2000, C=1, p=1, out_dim=1 (fp32 in / fp32 out).
// Memory-bound: 147.5 MB read + 147.5 MB write -> ~47 us floor at 6.3 TB/s
// mixed-stream ceiling (harness fillBuffer shows 6.7 TB/s write-only).
//
// v3 changes vs v2 (v2 ~66 us kernel slice, ~4.5 TB/s effective):
//  - 4x float4 per thread, loads issued before stores: 4 outstanding 16B
//    loads per thread instead of 1 (MLP was the suspected limiter vs the
//    6.29 TB/s float4-copy ubench).
//  - x load is now a PLAIN cached load (was nontemporal): x is 147 MB and
//    fits the 256 MB Infinity Cache, so it can stay LLC-resident across
//    timed graph replays. Store stays nontemporal so the out stream does
//    not evict x.
//  - Pure int32 indexing (all offsets < 2^31): drops 64-bit address math.

typedef float f4 __attribute__((ext_vector_type(4)));

static constexpr int kN4       = 500;     // N/4 float4 per t-row
static constexpr int kTN4      = 144000;  // T*N/4 float4 per batch
static constexpr int kPerBlock = 1024;    // 256 threads x 4 float4

__global__ __launch_bounds__(256) void ARModel_88880053223563_kernel(
    const f4* __restrict__ x,
    const float* __restrict__ w,
    const float* __restrict__ bias,
    f4* __restrict__ out)
{
    const int rem0 = blockIdx.x * kPerBlock + threadIdx.x;  // f4 idx in batch
    const int base = blockIdx.y * kTN4;                     // batch offset (f4)
    const float wv = w[0];     // uniform scalar loads (s_load broadcast)
    const float bv = bias[0];

    f4 v[4];
    // Phase 1: issue all loads (4 outstanding vmem ops per thread).
    #pragma unroll
    for (int j = 0; j < 4; ++j) {
        const int rem = rem0 + j * 256;
        v[j] = (f4){0.f, 0.f, 0.f, 0.f};    // t==0 row stays zero
        if (rem >= kN4 && rem < kTN4) {
            const f4 xi = x[base + rem - kN4];   // cached: keep x LLC-resident
            v[j].x = fmaf(xi.x, wv, bv);
            v[j].y = fmaf(xi.y, wv, bv);
            v[j].z = fmaf(xi.z, wv, bv);
            v[j].w = fmaf(xi.w, wv, bv);
        }
    }
    // Phase 2: streaming stores (touch-once, bypass LLC).
    #pragma unroll
    for (int j = 0; j < 4; ++j) {
        const int rem = rem0 + j * 256;
        if (rem < kTN4) {
            __builtin_nontemporal_store(v[j], &out[base + rem]);
        }
    }
}

extern "C" void kernel_launch(void* const* d_in, const int* in_sizes, int n_in,
                              void* d_out, int out_size, void* d_ws, size_t ws_size,
                              hipStream_t stream) {
    const f4*    x    = (const f4*)d_in[0];
    const float* w    = (const float*)d_in[1];
    const float* bias = (const float*)d_in[2];
    f4*          out  = (f4*)d_out;

    // 144000 float4 per batch -> 141 blocks of 1024 f4 (tail guard), 64 batches.
    dim3 grid((kTN4 + kPerBlock - 1) / kPerBlock, 64);
    ARModel_88880053223563_kernel<<<grid, dim3(256), 0, stream>>>(x, w, bias, out);
}

// Round 2
// 242.668 us; speedup vs baseline: 1.0675x; 1.0675x over previous
//
#include <hip/hip_runtime.h>

// ARModel: out[b,t,n,0] = (t==0) ? 0 : x[b,t-1,n,0]*w[0,0,0] + bias[0]
// B=64, T=288, N=2000, C=1, p=1, out_dim=1 (fp32 in / fp32 out).
// Memory-bound: 147.5 MB read + 147.5 MB write. fillBuffer shows 6.7 TB/s
// write-only; float4-copy ubench 6.29 TB/s -> floor ~47-55 us mixed.
//
// History:
//  v2: all-NT, 1 f4/thread            -> ~65 us kernel slice (4.5 TB/s user)
//  v3: cached loads + 4 f4/thread     -> 88.4 us REGRESSION. FETCH halved
//      (LLC hits) but cached-read path + NT-store mix ran at 2.5 TB/s HBM.
//      Lesson: keep BOTH streams nontemporal on this chip.
//  v4 (this): revert to all-NT (v2's best-known config), change ONE thing:
//      8 f4 per thread with all loads issued up front (8 outstanding 16B
//      loads/thread vs v2's 1) to test the MLP hypothesis cleanly.
//      Guard-free fast path for interior blocks (hygiene, not the lever).

typedef float f4 __attribute__((ext_vector_type(4)));

static constexpr int kN4       = 500;                // N/4 float4 per t-row
static constexpr int kTN4      = 144000;             // T*N/4 float4 per batch
static constexpr int kJ        = 8;                  // f4 per thread
static constexpr int kPerBlock = 256 * kJ;           // 2048 f4 per block
static constexpr int kBlocksX  = (kTN4 + kPerBlock - 1) / kPerBlock;  // 71

__global__ __launch_bounds__(256) void ARModel_88880053223563_kernel(
    const f4* __restrict__ x,
    const float* __restrict__ w,
    const float* __restrict__ bias,
    f4* __restrict__ out)
{
    const int tid  = threadIdx.x;
    const int bx   = blockIdx.x;
    const int rem0 = bx * kPerBlock + tid;           // f4 idx within batch
    const int base = blockIdx.y * kTN4;              // batch offset (f4)
    const float wv = w[0];                           // s_load broadcast
    const float bv = bias[0];

    if (bx != 0 && bx != kBlocksX - 1) {
        // Fast path: no bounds checks, no t==0 row. 8 NT loads in flight.
        f4 v[kJ];
        #pragma unroll
        for (int j = 0; j < kJ; ++j)
            v[j] = __builtin_nontemporal_load(&x[base + rem0 + j * 256 - kN4]);
        #pragma unroll
        for (int j = 0; j < kJ; ++j) {
            f4 o;
            o.x = fmaf(v[j].x, wv, bv);
            o.y = fmaf(v[j].y, wv, bv);
            o.z = fmaf(v[j].z, wv, bv);
            o.w = fmaf(v[j].w, wv, bv);
            __builtin_nontemporal_store(o, &out[base + rem0 + j * 256]);
        }
    } else {
        // Edge blocks: block 0 holds the t==0 zero rows (rem < 500),
        // block kBlocksX-1 holds the tail (rem >= kTN4).
        #pragma unroll
        for (int j = 0; j < kJ; ++j) {
            const int rem = rem0 + j * 256;
            if (rem >= kTN4) continue;
            f4 o = (f4){0.f, 0.f, 0.f, 0.f};   // t==0 rows: zero, NO bias
            if (rem >= kN4) {
                const f4 xi = __builtin_nontemporal_load(&x[base + rem - kN4]);
                o.x = fmaf(xi.x, wv, bv);
                o.y = fmaf(xi.y, wv, bv);
                o.z = fmaf(xi.z, wv, bv);
                o.w = fmaf(xi.w, wv, bv);
            }
            __builtin_nontemporal_store(o, &out[base + rem]);
        }
    }
}

extern "C" void kernel_launch(void* const* d_in, const int* in_sizes, int n_in,
                              void* d_out, int out_size, void* d_ws, size_t ws_size,
                              hipStream_t stream) {
    const f4*    x    = (const f4*)d_in[0];
    const float* w    = (const float*)d_in[1];
    const float* bias = (const float*)d_in[2];
    f4*          out  = (f4*)d_out;

    // 144000 f4 per batch -> 71 blocks of 2048 f4 (tail guard), 64 batches.
    dim3 grid(kBlocksX, 64);
    ARModel_88880053223563_kernel<<<grid, dim3(256), 0, stream>>>(x, w, bias, out);
}